// Round 3
// baseline (685.124 us; speedup 1.0000x reference)
//
#include <hip/hip_runtime.h>
#include <cstddef>

#define NB 4
#define NN 512
#define NH 256
#define NHEADS 8
#define NSUBH 32
#define NFF 1024
#define LNEPS 1e-5f

// ---------------------------------------------------------------------------
// Kernel A: V projection. v[b,h,j,d] = S[b,j,:]·Wv[:,h*32+d] + bv[h*32+d]
// ---------------------------------------------------------------------------
__global__ __launch_bounds__(256) void vproj_kernel(
    const float* __restrict__ S, const float* __restrict__ Wv,
    const float* __restrict__ bv, float* __restrict__ v_ws)
{
    __shared__ float srow[8][NH];
    const int t = threadIdx.x;
    const int row0 = blockIdx.x * 8;
    #pragma unroll
    for (int r = 0; r < 8; ++r) srow[r][t] = S[(size_t)(row0 + r) * NH + t];
    __syncthreads();

    float acc[8];
    #pragma unroll
    for (int r = 0; r < 8; ++r) acc[r] = 0.0f;
    for (int e = 0; e < NH; e += 4) {
        const float w0 = Wv[(size_t)(e + 0) * NH + t];
        const float w1 = Wv[(size_t)(e + 1) * NH + t];
        const float w2 = Wv[(size_t)(e + 2) * NH + t];
        const float w3 = Wv[(size_t)(e + 3) * NH + t];
        #pragma unroll
        for (int r = 0; r < 8; ++r) {
            const float4 x4 = *(const float4*)&srow[r][e];
            acc[r] = fmaf(x4.x, w0, fmaf(x4.y, w1, fmaf(x4.z, w2, fmaf(x4.w, w3, acc[r]))));
        }
    }
    const float bvc = bv[t];
    const int h = t >> 5, d = t & 31;
    const int b = row0 / NN;
    const int jbase = row0 & (NN - 1);
    #pragma unroll
    for (int r = 0; r < 8; ++r)
        v_ws[((size_t)(b * NHEADS + h) * NN + (size_t)(jbase + r)) * NSUBH + d] = acc[r] + bvc;
}

// ---------------------------------------------------------------------------
// Kernel B: fused scores + softmax + attn-write + ctx.
// grid = B*N = 2048 blocks (one per (b,i)), 256 threads = 4 waves.
// Phase 1: column-chunked LDS staging of T (coalesced global loads), each
// thread owns rows tid and tid+256 and accumulates all 8 heads in-lane with
// wave-uniform (scalar) Wqk loads. LDS writes/reads swizzled: the 16B unit
// of (row, q) lives at unit row*4 + ((q + (row>>1)) & 3)  -> conflict-free.
// ---------------------------------------------------------------------------
__global__ __launch_bounds__(256, 4) void attn_kernel(
    const float* __restrict__ T, const int* __restrict__ masks,
    const float* __restrict__ Wqk, const float* __restrict__ v_ws,
    float* __restrict__ attn_out, float* __restrict__ ctx_out)
{
    __shared__ float tbuf[NN * 16];      // 32 KB: chunk of 16 e-cols x 512 rows
    __shared__ float maddv[NN];          // 2 KB
    float (*sc)[NHEADS] = (float(*)[NHEADS])tbuf;  // overlay after phase 1

    const int tid = threadIdx.x;
    const int b = blockIdx.x >> 9;
    const int i = blockIdx.x & (NN - 1);

    const int mi = masks[b * NN + i];
    for (int j = tid; j < NN; j += 256)
        maddv[j] = (mi != 0 && masks[b * NN + j] != 0) ? 0.0f : -1000.0f;

    const float4* Tv = (const float4*)(T + (size_t)(b * NN + i) * NN * NH);

    // Per-thread staging map: flat 16B unit f = tid + 256k -> row=f>>2, q=f&3.
    int gunit[8], lunit[8];
    #pragma unroll
    for (int k = 0; k < 8; ++k) {
        const int f = tid + 256 * k;
        const int row = f >> 2, q = f & 3;
        gunit[k] = row * 64 + q;                       // + 4*chunk at use
        lunit[k] = row * 4 + ((q + (row >> 1)) & 3);   // swizzled dest
    }

    float a0[8], a1[8];
    #pragma unroll
    for (int h = 0; h < 8; ++h) { a0[h] = 0.0f; a1[h] = 0.0f; }

    // read units for this thread's two rows (swizzle rotation same for both)
    const int r0 = tid, r1 = tid + 256;
    const int rot = (r0 >> 1) & 3;

    float4 sreg[8];
    #pragma unroll
    for (int k = 0; k < 8; ++k) sreg[k] = Tv[gunit[k]];   // chunk 0 in flight

    for (int c = 0; c < 16; ++c) {
        __syncthreads();                    // buffer free (prev compute done)
        #pragma unroll
        for (int k = 0; k < 8; ++k)         // waits vmcnt for sreg, writes LDS
            ((float4*)tbuf)[lunit[k]] = sreg[k];
        __syncthreads();                    // chunk visible
        if (c < 15) {
            #pragma unroll
            for (int k = 0; k < 8; ++k)     // issue next chunk early (T14)
                sreg[k] = Tv[gunit[k] + 4 * (c + 1)];
        }
        const float* wbase = Wqk + c * 16 * 8;
        #pragma unroll
        for (int q = 0; q < 4; ++q) {
            const float4 t0 = ((const float4*)tbuf)[r0 * 4 + ((q + rot) & 3)];
            const float4 t1 = ((const float4*)tbuf)[r1 * 4 + ((q + rot) & 3)];
            const float* wp = wbase + q * 32;   // wave-uniform -> s_load
            #pragma unroll
            for (int h = 0; h < 8; ++h) {
                a0[h] = fmaf(t0.x, wp[h], fmaf(t0.y, wp[8 + h],
                        fmaf(t0.z, wp[16 + h], fmaf(t0.w, wp[24 + h], a0[h]))));
                a1[h] = fmaf(t1.x, wp[h], fmaf(t1.y, wp[8 + h],
                        fmaf(t1.z, wp[16 + h], fmaf(t1.w, wp[24 + h], a1[h]))));
            }
        }
    }
    __syncthreads();   // done with tbuf as T-chunk; reuse as sc

    *(float4*)&sc[r0][0] = make_float4(a0[0], a0[1], a0[2], a0[3]);
    *(float4*)&sc[r0][4] = make_float4(a0[4], a0[5], a0[6], a0[7]);
    *(float4*)&sc[r1][0] = make_float4(a1[0], a1[1], a1[2], a1[3]);
    *(float4*)&sc[r1][4] = make_float4(a1[4], a1[5], a1[6], a1[7]);
    __syncthreads();

    // Phase 2: softmax per head; 32 threads per head.
    const int h = tid >> 5;
    const int l32 = tid & 31;
    float vals[16];
    float m = -1e30f;
    #pragma unroll
    for (int k = 0; k < 16; ++k) {
        const int j = l32 + 32 * k;
        const float s = sc[j][h] + maddv[j];
        vals[k] = s;
        m = fmaxf(m, s);
    }
    #pragma unroll
    for (int off = 16; off >= 1; off >>= 1) m = fmaxf(m, __shfl_xor(m, off, 32));
    float sum = 0.0f;
    #pragma unroll
    for (int k = 0; k < 16; ++k) {
        const float e = __expf(vals[k] - m);
        vals[k] = e;
        sum += e;
    }
    #pragma unroll
    for (int off = 16; off >= 1; off >>= 1) sum += __shfl_xor(sum, off, 32);
    const float inv = 1.0f / sum;
    float* arow = attn_out + ((size_t)(b * NHEADS + h) * NN + i) * NN;
    #pragma unroll
    for (int k = 0; k < 16; ++k) {
        const int j = l32 + 32 * k;
        const float p = vals[k] * inv;
        sc[j][h] = p;
        arow[j] = p;
    }
    __syncthreads();

    // Phase 3: ctx[h][d] = sum_j P[h][j] * v[b,h,j,d]
    const int d = l32;
    const float* vp = v_ws + (size_t)(b * NHEADS + h) * NN * NSUBH + d;
    float acc = 0.0f;
    #pragma unroll 8
    for (int j = 0; j < NN; ++j)
        acc = fmaf(sc[j][h], vp[(size_t)j * NSUBH], acc);
    ctx_out[(size_t)(b * NN + i) * NH + h * NSUBH + d] = acc;
}

// ---------------------------------------------------------------------------
// Kernel C: tail. x=relu(ctx·Wo+bo); x1=LN(S+x); y=relu(x1·W1+b1)·W2+b2;
// out=LN(x1+y). 8 rows per block, 256 blocks, 256 threads.
// ---------------------------------------------------------------------------
__global__ __launch_bounds__(256) void tail_kernel(
    const float* __restrict__ ctx, const float* __restrict__ S,
    const float* __restrict__ Wo, const float* __restrict__ bo,
    const float* __restrict__ g0, const float* __restrict__ beta0,
    const float* __restrict__ W1, const float* __restrict__ b1,
    const float* __restrict__ W2, const float* __restrict__ b2,
    const float* __restrict__ g1, const float* __restrict__ beta1,
    float* __restrict__ out)
{
    __shared__ float xin[8][NH];
    __shared__ float x1[8][NH];
    __shared__ float ybuf[8][NFF];
    const int t = threadIdx.x;
    const int row0 = blockIdx.x * 8;

    #pragma unroll
    for (int r = 0; r < 8; ++r) xin[r][t] = ctx[(size_t)(row0 + r) * NH + t];
    __syncthreads();

    // GEMM1: ctx @ Wo
    float acc[8];
    #pragma unroll
    for (int r = 0; r < 8; ++r) acc[r] = 0.0f;
    for (int e = 0; e < NH; e += 4) {
        const float w0 = Wo[(size_t)(e + 0) * NH + t];
        const float w1 = Wo[(size_t)(e + 1) * NH + t];
        const float w2 = Wo[(size_t)(e + 2) * NH + t];
        const float w3 = Wo[(size_t)(e + 3) * NH + t];
        #pragma unroll
        for (int r = 0; r < 8; ++r) {
            const float4 x4 = *(const float4*)&xin[r][e];
            acc[r] = fmaf(x4.x, w0, fmaf(x4.y, w1, fmaf(x4.z, w2, fmaf(x4.w, w3, acc[r]))));
        }
    }
    const float boc = bo[t];
    #pragma unroll
    for (int r = 0; r < 8; ++r) {
        const float xv = fmaxf(acc[r] + boc, 0.0f);
        x1[r][t] = S[(size_t)(row0 + r) * NH + t] + xv;
    }
    __syncthreads();

    // LN0 (in place on x1)
    {
        const int wv = t >> 6, ln = t & 63;
        #pragma unroll
        for (int rr = 0; rr < 2; ++rr) {
            const int r = wv * 2 + rr;
            float s1 = 0.0f, s2 = 0.0f;
            #pragma unroll
            for (int k = 0; k < 4; ++k) {
                const float z = x1[r][ln + 64 * k];
                s1 += z; s2 += z * z;
            }
            #pragma unroll
            for (int off = 32; off >= 1; off >>= 1) {
                s1 += __shfl_xor(s1, off);
                s2 += __shfl_xor(s2, off);
            }
            const float mu = s1 * (1.0f / NH);
            const float rsig = rsqrtf(s2 * (1.0f / NH) - mu * mu + LNEPS);
            #pragma unroll
            for (int k = 0; k < 4; ++k) {
                const int c = ln + 64 * k;
                x1[r][c] = (x1[r][c] - mu) * rsig * g0[c] + beta0[c];
            }
        }
    }
    __syncthreads();

    // GEMM2: x1 @ W1 (+b1, relu) -> ybuf
    float acc2[8][4];
    #pragma unroll
    for (int r = 0; r < 8; ++r)
        #pragma unroll
        for (int q = 0; q < 4; ++q) acc2[r][q] = 0.0f;
    for (int e = 0; e < NH; e += 4) {
        float4 x4[8];
        #pragma unroll
        for (int r = 0; r < 8; ++r) x4[r] = *(const float4*)&x1[r][e];
        #pragma unroll
        for (int q = 0; q < 4; ++q) {
            const float* wc = W1 + (size_t)e * NFF + (t + 256 * q);
            const float w0 = wc[0 * NFF], w1 = wc[1 * NFF], w2 = wc[2 * NFF], w3 = wc[3 * NFF];
            #pragma unroll
            for (int r = 0; r < 8; ++r)
                acc2[r][q] = fmaf(x4[r].x, w0, fmaf(x4[r].y, w1, fmaf(x4[r].z, w2, fmaf(x4[r].w, w3, acc2[r][q]))));
        }
    }
    #pragma unroll
    for (int q = 0; q < 4; ++q) {
        const float b1c = b1[t + 256 * q];
        #pragma unroll
        for (int r = 0; r < 8; ++r)
            ybuf[r][t + 256 * q] = fmaxf(acc2[r][q] + b1c, 0.0f);
    }
    __syncthreads();

    // GEMM3: ybuf @ W2 (+b2) + x1 residual
    float acc3[8];
    #pragma unroll
    for (int r = 0; r < 8; ++r) acc3[r] = 0.0f;
    for (int f = 0; f < NFF; f += 4) {
        const float w0 = W2[(size_t)(f + 0) * NH + t];
        const float w1 = W2[(size_t)(f + 1) * NH + t];
        const float w2 = W2[(size_t)(f + 2) * NH + t];
        const float w3 = W2[(size_t)(f + 3) * NH + t];
        #pragma unroll
        for (int r = 0; r < 8; ++r) {
            const float4 y4 = *(const float4*)&ybuf[r][f];
            acc3[r] = fmaf(y4.x, w0, fmaf(y4.y, w1, fmaf(y4.z, w2, fmaf(y4.w, w3, acc3[r]))));
        }
    }
    const float b2c = b2[t];
    #pragma unroll
    for (int r = 0; r < 8; ++r)
        xin[r][t] = x1[r][t] + acc3[r] + b2c;
    __syncthreads();

    // LN1 -> out
    {
        const int wv = t >> 6, ln = t & 63;
        #pragma unroll
        for (int rr = 0; rr < 2; ++rr) {
            const int r = wv * 2 + rr;
            float s1 = 0.0f, s2 = 0.0f;
            #pragma unroll
            for (int k = 0; k < 4; ++k) {
                const float z = xin[r][ln + 64 * k];
                s1 += z; s2 += z * z;
            }
            #pragma unroll
            for (int off = 32; off >= 1; off >>= 1) {
                s1 += __shfl_xor(s1, off);
                s2 += __shfl_xor(s2, off);
            }
            const float mu = s1 * (1.0f / NH);
            const float rsig = rsqrtf(s2 * (1.0f / NH) - mu * mu + LNEPS);
            #pragma unroll
            for (int k = 0; k < 4; ++k) {
                const int c = ln + 64 * k;
                out[(size_t)(row0 + r) * NH + c] = (xin[r][c] - mu) * rsig * g1[c] + beta1[c];
            }
        }
    }
}

// ---------------------------------------------------------------------------
extern "C" void kernel_launch(void* const* d_in, const int* in_sizes, int n_in,
                              void* d_out, int out_size, void* d_ws, size_t ws_size,
                              hipStream_t stream) {
    const float* S     = (const float*)d_in[0];
    const float* T     = (const float*)d_in[1];
    const int*   masks = (const int*)  d_in[2];
    const float* Wqk   = (const float*)d_in[3];
    const float* Wv    = (const float*)d_in[4];
    const float* bv    = (const float*)d_in[5];
    const float* Wo    = (const float*)d_in[6];
    const float* bo    = (const float*)d_in[7];
    const float* g0    = (const float*)d_in[8];
    const float* beta0 = (const float*)d_in[9];
    const float* W1    = (const float*)d_in[10];
    const float* b1    = (const float*)d_in[11];
    const float* W2    = (const float*)d_in[12];
    const float* b2    = (const float*)d_in[13];
    const float* g1    = (const float*)d_in[14];
    const float* beta1 = (const float*)d_in[15];

    float* out      = (float*)d_out;
    float* attn_out = out + (size_t)NB * NN * NH;
    float* v_ws     = (float*)d_ws;
    float* ctx      = out;

    vproj_kernel<<<NB * NN / 8, 256, 0, stream>>>(S, Wv, bv, v_ws);
    attn_kernel<<<NB * NN, 256, 0, stream>>>(T, masks, Wqk, v_ws, attn_out, ctx);
    tail_kernel<<<NB * NN / 8, 256, 0, stream>>>(ctx, S, Wo, bo, g0, beta0,
                                                 W1, b1, W2, b2, g1, beta1, out);
}

// Round 4
// 442.630 us; speedup vs baseline: 1.5478x; 1.5478x over previous
//
#include <hip/hip_runtime.h>
#include <cstddef>

#define NB 4
#define NN 512
#define NH 256
#define NHEADS 8
#define NSUBH 32
#define NFF 1024
#define LNEPS 1e-5f

// ---------------------------------------------------------------------------
// Kernel A: V projection. v[b,h,j,d] = S[b,j,:]·Wv[:,h*32+d] + bv[h*32+d]
// ---------------------------------------------------------------------------
__global__ __launch_bounds__(256) void vproj_kernel(
    const float* __restrict__ S, const float* __restrict__ Wv,
    const float* __restrict__ bv, float* __restrict__ v_ws)
{
    __shared__ float srow[8][NH];
    const int t = threadIdx.x;
    const int row0 = blockIdx.x * 8;
    #pragma unroll
    for (int r = 0; r < 8; ++r) srow[r][t] = S[(size_t)(row0 + r) * NH + t];
    __syncthreads();

    float acc[8];
    #pragma unroll
    for (int r = 0; r < 8; ++r) acc[r] = 0.0f;
    for (int e = 0; e < NH; e += 4) {
        const float w0 = Wv[(size_t)(e + 0) * NH + t];
        const float w1 = Wv[(size_t)(e + 1) * NH + t];
        const float w2 = Wv[(size_t)(e + 2) * NH + t];
        const float w3 = Wv[(size_t)(e + 3) * NH + t];
        #pragma unroll
        for (int r = 0; r < 8; ++r) {
            const float4 x4 = *(const float4*)&srow[r][e];
            acc[r] = fmaf(x4.x, w0, fmaf(x4.y, w1, fmaf(x4.z, w2, fmaf(x4.w, w3, acc[r]))));
        }
    }
    const float bvc = bv[t];
    const int h = t >> 5, d = t & 31;
    const int b = row0 / NN;
    const int jbase = row0 & (NN - 1);
    #pragma unroll
    for (int r = 0; r < 8; ++r)
        v_ws[((size_t)(b * NHEADS + h) * NN + (size_t)(jbase + r)) * NSUBH + d] = acc[r] + bvc;
}

// ---------------------------------------------------------------------------
// Kernel B: fused scores + softmax + attn-write + ctx.
// grid = B*N = 2048 blocks (one per (b,i)), 256 threads = 4 waves.
// Phase 1: thread owns rows tid and tid+256. Per iteration it loads one FULL
// 64B line per row (4 consecutive float4s, MSHR-merged, consumed immediately
// -> no L1-persistence dependence), then 256 in-lane FMAs with wave-uniform
// (scalar-loaded) Wqk. No cross-lane reductions, no barriers in phase 1.
// ---------------------------------------------------------------------------
__global__ __launch_bounds__(256, 4) void attn_kernel(
    const float* __restrict__ T, const int* __restrict__ masks,
    const float* __restrict__ Wqk, const float* __restrict__ v_ws,
    float* __restrict__ attn_out, float* __restrict__ ctx_out)
{
    __shared__ float sc[NN][NHEADS];   // scores, later normalized P (16 KB)
    __shared__ float maddv[NN];        // 2 KB
    const int tid = threadIdx.x;
    const int b = blockIdx.x >> 9;
    const int i = blockIdx.x & (NN - 1);

    const int mi = masks[b * NN + i];
    for (int j = tid; j < NN; j += 256)
        maddv[j] = (mi != 0 && masks[b * NN + j] != 0) ? 0.0f : -1000.0f;

    const float* Trow = T + (size_t)(b * NN + i) * NN * NH;

    const int j0 = tid, j1 = tid + 256;
    const float4* r0 = (const float4*)(Trow + (size_t)j0 * NH);
    const float4* r1 = (const float4*)(Trow + (size_t)j1 * NH);

    float a0[8], a1[8];
    #pragma unroll
    for (int h = 0; h < 8; ++h) { a0[h] = 0.0f; a1[h] = 0.0f; }

    for (int c = 0; c < 16; ++c) {
        float4 t0[4], t1[4];
        #pragma unroll
        for (int k = 0; k < 4; ++k) t0[k] = r0[4 * c + k];   // one 64B line
        #pragma unroll
        for (int k = 0; k < 4; ++k) t1[k] = r1[4 * c + k];   // one 64B line
        const float* wp = Wqk + c * 128;                     // wave-uniform
        #pragma unroll
        for (int k = 0; k < 4; ++k) {
            const float* w = wp + k * 32;
            #pragma unroll
            for (int h = 0; h < 8; ++h) {
                a0[h] = fmaf(t0[k].x, w[h], fmaf(t0[k].y, w[8 + h],
                        fmaf(t0[k].z, w[16 + h], fmaf(t0[k].w, w[24 + h], a0[h]))));
                a1[h] = fmaf(t1[k].x, w[h], fmaf(t1[k].y, w[8 + h],
                        fmaf(t1[k].z, w[16 + h], fmaf(t1[k].w, w[24 + h], a1[h]))));
            }
        }
    }
    *(float4*)&sc[j0][0] = make_float4(a0[0], a0[1], a0[2], a0[3]);
    *(float4*)&sc[j0][4] = make_float4(a0[4], a0[5], a0[6], a0[7]);
    *(float4*)&sc[j1][0] = make_float4(a1[0], a1[1], a1[2], a1[3]);
    *(float4*)&sc[j1][4] = make_float4(a1[4], a1[5], a1[6], a1[7]);
    __syncthreads();

    // Phase 2: softmax per head; 32 threads per head.
    const int h = tid >> 5;
    const int l32 = tid & 31;
    float vals[16];
    float m = -1e30f;
    #pragma unroll
    for (int k = 0; k < 16; ++k) {
        const int j = l32 + 32 * k;
        const float s = sc[j][h] + maddv[j];
        vals[k] = s;
        m = fmaxf(m, s);
    }
    #pragma unroll
    for (int off = 16; off >= 1; off >>= 1) m = fmaxf(m, __shfl_xor(m, off, 32));
    float sum = 0.0f;
    #pragma unroll
    for (int k = 0; k < 16; ++k) {
        const float e = __expf(vals[k] - m);
        vals[k] = e;
        sum += e;
    }
    #pragma unroll
    for (int off = 16; off >= 1; off >>= 1) sum += __shfl_xor(sum, off, 32);
    const float inv = 1.0f / sum;
    float* arow = attn_out + ((size_t)(b * NHEADS + h) * NN + i) * NN;
    #pragma unroll
    for (int k = 0; k < 16; ++k) {
        const int j = l32 + 32 * k;
        const float p = vals[k] * inv;
        sc[j][h] = p;
        arow[j] = p;
    }
    __syncthreads();

    // Phase 3: ctx[h][d] = sum_j P[h][j] * v[b,h,j,d]
    const int d = l32;
    const float* vp = v_ws + (size_t)(b * NHEADS + h) * NN * NSUBH + d;
    float acc = 0.0f;
    #pragma unroll 8
    for (int j = 0; j < NN; ++j)
        acc = fmaf(sc[j][h], vp[(size_t)j * NSUBH], acc);
    ctx_out[(size_t)(b * NN + i) * NH + h * NSUBH + d] = acc;
}

// ---------------------------------------------------------------------------
// Kernel C: tail. x=relu(ctx·Wo+bo); x1=LN(S+x); y=relu(x1·W1+b1)·W2+b2;
// out=LN(x1+y). 8 rows per block, 256 blocks, 256 threads.
// ---------------------------------------------------------------------------
__global__ __launch_bounds__(256) void tail_kernel(
    const float* __restrict__ ctx, const float* __restrict__ S,
    const float* __restrict__ Wo, const float* __restrict__ bo,
    const float* __restrict__ g0, const float* __restrict__ beta0,
    const float* __restrict__ W1, const float* __restrict__ b1,
    const float* __restrict__ W2, const float* __restrict__ b2,
    const float* __restrict__ g1, const float* __restrict__ beta1,
    float* __restrict__ out)
{
    __shared__ float xin[8][NH];
    __shared__ float x1[8][NH];
    __shared__ float ybuf[8][NFF];
    const int t = threadIdx.x;
    const int row0 = blockIdx.x * 8;

    #pragma unroll
    for (int r = 0; r < 8; ++r) xin[r][t] = ctx[(size_t)(row0 + r) * NH + t];
    __syncthreads();

    // GEMM1: ctx @ Wo
    float acc[8];
    #pragma unroll
    for (int r = 0; r < 8; ++r) acc[r] = 0.0f;
    for (int e = 0; e < NH; e += 4) {
        const float w0 = Wo[(size_t)(e + 0) * NH + t];
        const float w1 = Wo[(size_t)(e + 1) * NH + t];
        const float w2 = Wo[(size_t)(e + 2) * NH + t];
        const float w3 = Wo[(size_t)(e + 3) * NH + t];
        #pragma unroll
        for (int r = 0; r < 8; ++r) {
            const float4 x4 = *(const float4*)&xin[r][e];
            acc[r] = fmaf(x4.x, w0, fmaf(x4.y, w1, fmaf(x4.z, w2, fmaf(x4.w, w3, acc[r]))));
        }
    }
    const float boc = bo[t];
    #pragma unroll
    for (int r = 0; r < 8; ++r) {
        const float xv = fmaxf(acc[r] + boc, 0.0f);
        x1[r][t] = S[(size_t)(row0 + r) * NH + t] + xv;
    }
    __syncthreads();

    // LN0 (in place on x1)
    {
        const int wv = t >> 6, ln = t & 63;
        #pragma unroll
        for (int rr = 0; rr < 2; ++rr) {
            const int r = wv * 2 + rr;
            float s1 = 0.0f, s2 = 0.0f;
            #pragma unroll
            for (int k = 0; k < 4; ++k) {
                const float z = x1[r][ln + 64 * k];
                s1 += z; s2 += z * z;
            }
            #pragma unroll
            for (int off = 32; off >= 1; off >>= 1) {
                s1 += __shfl_xor(s1, off);
                s2 += __shfl_xor(s2, off);
            }
            const float mu = s1 * (1.0f / NH);
            const float rsig = rsqrtf(s2 * (1.0f / NH) - mu * mu + LNEPS);
            #pragma unroll
            for (int k = 0; k < 4; ++k) {
                const int c = ln + 64 * k;
                x1[r][c] = (x1[r][c] - mu) * rsig * g0[c] + beta0[c];
            }
        }
    }
    __syncthreads();

    // GEMM2: x1 @ W1 (+b1, relu) -> ybuf
    float acc2[8][4];
    #pragma unroll
    for (int r = 0; r < 8; ++r)
        #pragma unroll
        for (int q = 0; q < 4; ++q) acc2[r][q] = 0.0f;
    for (int e = 0; e < NH; e += 4) {
        float4 x4[8];
        #pragma unroll
        for (int r = 0; r < 8; ++r) x4[r] = *(const float4*)&x1[r][e];
        #pragma unroll
        for (int q = 0; q < 4; ++q) {
            const float* wc = W1 + (size_t)e * NFF + (t + 256 * q);
            const float w0 = wc[0 * NFF], w1 = wc[1 * NFF], w2 = wc[2 * NFF], w3 = wc[3 * NFF];
            #pragma unroll
            for (int r = 0; r < 8; ++r)
                acc2[r][q] = fmaf(x4[r].x, w0, fmaf(x4[r].y, w1, fmaf(x4[r].z, w2, fmaf(x4[r].w, w3, acc2[r][q]))));
        }
    }
    #pragma unroll
    for (int q = 0; q < 4; ++q) {
        const float b1c = b1[t + 256 * q];
        #pragma unroll
        for (int r = 0; r < 8; ++r)
            ybuf[r][t + 256 * q] = fmaxf(acc2[r][q] + b1c, 0.0f);
    }
    __syncthreads();

    // GEMM3: ybuf @ W2 (+b2) + x1 residual
    float acc3[8];
    #pragma unroll
    for (int r = 0; r < 8; ++r) acc3[r] = 0.0f;
    for (int f = 0; f < NFF; f += 4) {
        const float w0 = W2[(size_t)(f + 0) * NH + t];
        const float w1 = W2[(size_t)(f + 1) * NH + t];
        const float w2 = W2[(size_t)(f + 2) * NH + t];
        const float w3 = W2[(size_t)(f + 3) * NH + t];
        #pragma unroll
        for (int r = 0; r < 8; ++r) {
            const float4 y4 = *(const float4*)&ybuf[r][f];
            acc3[r] = fmaf(y4.x, w0, fmaf(y4.y, w1, fmaf(y4.z, w2, fmaf(y4.w, w3, acc3[r]))));
        }
    }
    const float b2c = b2[t];
    #pragma unroll
    for (int r = 0; r < 8; ++r)
        xin[r][t] = x1[r][t] + acc3[r] + b2c;
    __syncthreads();

    // LN1 -> out
    {
        const int wv = t >> 6, ln = t & 63;
        #pragma unroll
        for (int rr = 0; rr < 2; ++rr) {
            const int r = wv * 2 + rr;
            float s1 = 0.0f, s2 = 0.0f;
            #pragma unroll
            for (int k = 0; k < 4; ++k) {
                const float z = xin[r][ln + 64 * k];
                s1 += z; s2 += z * z;
            }
            #pragma unroll
            for (int off = 32; off >= 1; off >>= 1) {
                s1 += __shfl_xor(s1, off);
                s2 += __shfl_xor(s2, off);
            }
            const float mu = s1 * (1.0f / NH);
            const float rsig = rsqrtf(s2 * (1.0f / NH) - mu * mu + LNEPS);
            #pragma unroll
            for (int k = 0; k < 4; ++k) {
                const int c = ln + 64 * k;
                out[(size_t)(row0 + r) * NH + c] = (xin[r][c] - mu) * rsig * g1[c] + beta1[c];
            }
        }
    }
}

// ---------------------------------------------------------------------------
extern "C" void kernel_launch(void* const* d_in, const int* in_sizes, int n_in,
                              void* d_out, int out_size, void* d_ws, size_t ws_size,
                              hipStream_t stream) {
    const float* S     = (const float*)d_in[0];
    const float* T     = (const float*)d_in[1];
    const int*   masks = (const int*)  d_in[2];
    const float* Wqk   = (const float*)d_in[3];
    const float* Wv    = (const float*)d_in[4];
    const float* bv    = (const float*)d_in[5];
    const float* Wo    = (const float*)d_in[6];
    const float* bo    = (const float*)d_in[7];
    const float* g0    = (const float*)d_in[8];
    const float* beta0 = (const float*)d_in[9];
    const float* W1    = (const float*)d_in[10];
    const float* b1    = (const float*)d_in[11];
    const float* W2    = (const float*)d_in[12];
    const float* b2    = (const float*)d_in[13];
    const float* g1    = (const float*)d_in[14];
    const float* beta1 = (const float*)d_in[15];

    float* out      = (float*)d_out;
    float* attn_out = out + (size_t)NB * NN * NH;
    float* v_ws     = (float*)d_ws;
    float* ctx      = out;

    vproj_kernel<<<NB * NN / 8, 256, 0, stream>>>(S, Wv, bv, v_ws);
    attn_kernel<<<NB * NN, 256, 0, stream>>>(T, masks, Wqk, v_ws, attn_out, ctx);
    tail_kernel<<<NB * NN / 8, 256, 0, stream>>>(ctx, S, Wo, bo, g0, beta0,
                                                 W1, b1, W2, b2, g1, beta1, out);
}

// Round 5
// 415.612 us; speedup vs baseline: 1.6485x; 1.0650x over previous
//
#include <hip/hip_runtime.h>
#include <cstddef>

#define NB 4
#define NN 512
#define NH 256
#define NHEADS 8
#define NSUBH 32
#define NFF 1024
#define LNEPS 1e-5f

// ---------------------------------------------------------------------------
// Kernel A: V projection. v[b,h,j,d] = S[b,j,:]·Wv[:,h*32+d] + bv[h*32+d]
// ---------------------------------------------------------------------------
__global__ __launch_bounds__(256) void vproj_kernel(
    const float* __restrict__ S, const float* __restrict__ Wv,
    const float* __restrict__ bv, float* __restrict__ v_ws)
{
    __shared__ float srow[8][NH];
    const int t = threadIdx.x;
    const int row0 = blockIdx.x * 8;
    #pragma unroll
    for (int r = 0; r < 8; ++r) srow[r][t] = S[(size_t)(row0 + r) * NH + t];
    __syncthreads();

    float acc[8];
    #pragma unroll
    for (int r = 0; r < 8; ++r) acc[r] = 0.0f;
    for (int e = 0; e < NH; e += 4) {
        const float w0 = Wv[(size_t)(e + 0) * NH + t];
        const float w1 = Wv[(size_t)(e + 1) * NH + t];
        const float w2 = Wv[(size_t)(e + 2) * NH + t];
        const float w3 = Wv[(size_t)(e + 3) * NH + t];
        #pragma unroll
        for (int r = 0; r < 8; ++r) {
            const float4 x4 = *(const float4*)&srow[r][e];
            acc[r] = fmaf(x4.x, w0, fmaf(x4.y, w1, fmaf(x4.z, w2, fmaf(x4.w, w3, acc[r]))));
        }
    }
    const float bvc = bv[t];
    const int h = t >> 5, d = t & 31;
    const int b = row0 / NN;
    const int jbase = row0 & (NN - 1);
    #pragma unroll
    for (int r = 0; r < 8; ++r)
        v_ws[((size_t)(b * NHEADS + h) * NN + (size_t)(jbase + r)) * NSUBH + d] = acc[r] + bvc;
}

// ---------------------------------------------------------------------------
// Kernel B: fused scores + softmax + attn-write + ctx.
// grid = B*N = 2048 blocks (one per (b,i)), 256 threads = 4 waves.
// Phase 1: wave w owns rows [w*128, w*128+128), 2 rows per iteration.
// Each row is loaded with ONE fully-coalesced wave instruction (64 lanes x
// 16B = the whole 1KB row). Lane l holds e=4l..4l+3 and its 32 loop-invariant
// Wqk weights in registers. Reduction = value-splitting butterfly:
// steps xor1/2/4 halve the live accumulators (4,2,1 exchanged), then 3
// single-value steps -> 10 shuffles + 10 adds per row instead of 48+48.
// After the butterfly lane l holds the full score of head
// H(l) = 4*(l&1) + (l&2) + ((l&4)>>2); lanes 0..15 write both rows to LDS.
// ---------------------------------------------------------------------------
__global__ __launch_bounds__(256) void attn_kernel(
    const float* __restrict__ T, const int* __restrict__ masks,
    const float* __restrict__ Wqk, const float* __restrict__ v_ws,
    float* __restrict__ attn_out, float* __restrict__ ctx_out)
{
    __shared__ float sc[NN][NHEADS];   // scores, later normalized P (16 KB)
    __shared__ float maddv[NN];        // 2 KB
    const int tid = threadIdx.x;
    const int lane = tid & 63;
    const int wave = tid >> 6;
    const int b = blockIdx.x >> 9;
    const int i = blockIdx.x & (NN - 1);

    const int mi = masks[b * NN + i];
    for (int j = tid; j < NN; j += 256)
        maddv[j] = (mi != 0 && masks[b * NN + j] != 0) ? 0.0f : -1000.0f;

    // preload Wqk rows e = 4*lane .. 4*lane+3 (32 consecutive floats per lane)
    float wq[4][8];
    {
        const float4* wp = (const float4*)(Wqk + lane * 32);
        #pragma unroll
        for (int q = 0; q < 8; ++q) {
            const float4 w4 = wp[q];
            const int k = q >> 1, h0 = (q & 1) * 4;
            wq[k][h0 + 0] = w4.x; wq[k][h0 + 1] = w4.y;
            wq[k][h0 + 2] = w4.z; wq[k][h0 + 3] = w4.w;
        }
    }
    const int Hh = 4 * (lane & 1) + (lane & 2) + ((lane >> 2) & 1);
    const bool k1 = (lane & 1) != 0, k2 = (lane & 2) != 0, k4 = (lane & 4) != 0;

    const float* Trow = T + (size_t)(b * NN + i) * NN * NH;
    const int rbase = wave * 128;

    #pragma unroll 2
    for (int it = 0; it < 64; ++it) {
        const int row0 = rbase + 2 * it, row1 = row0 + 1;
        const float4 t0 = ((const float4*)(Trow + (size_t)row0 * NH))[lane];
        const float4 t1 = ((const float4*)(Trow + (size_t)row1 * NH))[lane];

        float p0[8], p1[8];
        #pragma unroll
        for (int h = 0; h < 8; ++h) {
            p0[h] = fmaf(t0.x, wq[0][h], fmaf(t0.y, wq[1][h],
                    fmaf(t0.z, wq[2][h], t0.w * wq[3][h])));
            p1[h] = fmaf(t1.x, wq[0][h], fmaf(t1.y, wq[1][h],
                    fmaf(t1.z, wq[2][h], t1.w * wq[3][h])));
        }
        // step A: xor 1, exchange 4 values
        #pragma unroll
        for (int k = 0; k < 4; ++k) {
            const float sA0 = k1 ? p0[k] : p0[k + 4];
            const float sA1 = k1 ? p1[k] : p1[k + 4];
            const float rA0 = __shfl_xor(sA0, 1);
            const float rA1 = __shfl_xor(sA1, 1);
            p0[k] = (k1 ? p0[k + 4] : p0[k]) + rA0;
            p1[k] = (k1 ? p1[k + 4] : p1[k]) + rA1;
        }
        // step B: xor 2, exchange 2 values
        #pragma unroll
        for (int k = 0; k < 2; ++k) {
            const float sB0 = k2 ? p0[k] : p0[k + 2];
            const float sB1 = k2 ? p1[k] : p1[k + 2];
            const float rB0 = __shfl_xor(sB0, 2);
            const float rB1 = __shfl_xor(sB1, 2);
            p0[k] = (k2 ? p0[k + 2] : p0[k]) + rB0;
            p1[k] = (k2 ? p1[k + 2] : p1[k]) + rB1;
        }
        // step C: xor 4, exchange 1 value
        float s0, s1;
        {
            const float sC0 = k4 ? p0[0] : p0[1];
            const float sC1 = k4 ? p1[0] : p1[1];
            const float rC0 = __shfl_xor(sC0, 4);
            const float rC1 = __shfl_xor(sC1, 4);
            s0 = (k4 ? p0[1] : p0[0]) + rC0;
            s1 = (k4 ? p1[1] : p1[0]) + rC1;
        }
        // steps D/E/F: single-value butterfly over remaining lane bits
        s0 += __shfl_xor(s0, 8);  s1 += __shfl_xor(s1, 8);
        s0 += __shfl_xor(s0, 16); s1 += __shfl_xor(s1, 16);
        s0 += __shfl_xor(s0, 32); s1 += __shfl_xor(s1, 32);

        if (lane < 8)       sc[row0][Hh] = s0;
        else if (lane < 16) sc[row1][Hh] = s1;
    }
    __syncthreads();

    // Phase 2: softmax per head; 32 threads per head.
    const int h = tid >> 5;
    const int l32 = tid & 31;
    float vals[16];
    float m = -1e30f;
    #pragma unroll
    for (int k = 0; k < 16; ++k) {
        const int j = l32 + 32 * k;
        const float s = sc[j][h] + maddv[j];
        vals[k] = s;
        m = fmaxf(m, s);
    }
    #pragma unroll
    for (int off = 16; off >= 1; off >>= 1) m = fmaxf(m, __shfl_xor(m, off, 32));
    float sum = 0.0f;
    #pragma unroll
    for (int k = 0; k < 16; ++k) {
        const float e = __expf(vals[k] - m);
        vals[k] = e;
        sum += e;
    }
    #pragma unroll
    for (int off = 16; off >= 1; off >>= 1) sum += __shfl_xor(sum, off, 32);
    const float inv = 1.0f / sum;
    float* arow = attn_out + ((size_t)(b * NHEADS + h) * NN + i) * NN;
    #pragma unroll
    for (int k = 0; k < 16; ++k) {
        const int j = l32 + 32 * k;
        const float p = vals[k] * inv;
        sc[j][h] = p;
        arow[j] = p;
    }
    __syncthreads();

    // Phase 3: ctx[h][d] = sum_j P[h][j] * v[b,h,j,d]
    const int d = l32;
    const float* vp = v_ws + (size_t)(b * NHEADS + h) * NN * NSUBH + d;
    float acc = 0.0f;
    #pragma unroll 8
    for (int j = 0; j < NN; ++j)
        acc = fmaf(sc[j][h], vp[(size_t)j * NSUBH], acc);
    ctx_out[(size_t)(b * NN + i) * NH + h * NSUBH + d] = acc;
}

// ---------------------------------------------------------------------------
// Kernel C: tail. x=relu(ctx·Wo+bo); x1=LN(S+x); y=relu(x1·W1+b1)·W2+b2;
// out=LN(x1+y). 8 rows per block, 256 blocks, 256 threads.
// ---------------------------------------------------------------------------
__global__ __launch_bounds__(256) void tail_kernel(
    const float* __restrict__ ctx, const float* __restrict__ S,
    const float* __restrict__ Wo, const float* __restrict__ bo,
    const float* __restrict__ g0, const float* __restrict__ beta0,
    const float* __restrict__ W1, const float* __restrict__ b1,
    const float* __restrict__ W2, const float* __restrict__ b2,
    const float* __restrict__ g1, const float* __restrict__ beta1,
    float* __restrict__ out)
{
    __shared__ float xin[8][NH];
    __shared__ float x1[8][NH];
    __shared__ float ybuf[8][NFF];
    const int t = threadIdx.x;
    const int row0 = blockIdx.x * 8;

    #pragma unroll
    for (int r = 0; r < 8; ++r) xin[r][t] = ctx[(size_t)(row0 + r) * NH + t];
    __syncthreads();

    // GEMM1: ctx @ Wo
    float acc[8];
    #pragma unroll
    for (int r = 0; r < 8; ++r) acc[r] = 0.0f;
    for (int e = 0; e < NH; e += 4) {
        const float w0 = Wo[(size_t)(e + 0) * NH + t];
        const float w1 = Wo[(size_t)(e + 1) * NH + t];
        const float w2 = Wo[(size_t)(e + 2) * NH + t];
        const float w3 = Wo[(size_t)(e + 3) * NH + t];
        #pragma unroll
        for (int r = 0; r < 8; ++r) {
            const float4 x4 = *(const float4*)&xin[r][e];
            acc[r] = fmaf(x4.x, w0, fmaf(x4.y, w1, fmaf(x4.z, w2, fmaf(x4.w, w3, acc[r]))));
        }
    }
    const float boc = bo[t];
    #pragma unroll
    for (int r = 0; r < 8; ++r) {
        const float xv = fmaxf(acc[r] + boc, 0.0f);
        x1[r][t] = S[(size_t)(row0 + r) * NH + t] + xv;
    }
    __syncthreads();

    // LN0 (in place on x1)
    {
        const int wv = t >> 6, ln = t & 63;
        #pragma unroll
        for (int rr = 0; rr < 2; ++rr) {
            const int r = wv * 2 + rr;
            float s1 = 0.0f, s2 = 0.0f;
            #pragma unroll
            for (int k = 0; k < 4; ++k) {
                const float z = x1[r][ln + 64 * k];
                s1 += z; s2 += z * z;
            }
            #pragma unroll
            for (int off = 32; off >= 1; off >>= 1) {
                s1 += __shfl_xor(s1, off);
                s2 += __shfl_xor(s2, off);
            }
            const float mu = s1 * (1.0f / NH);
            const float rsig = rsqrtf(s2 * (1.0f / NH) - mu * mu + LNEPS);
            #pragma unroll
            for (int k = 0; k < 4; ++k) {
                const int c = ln + 64 * k;
                x1[r][c] = (x1[r][c] - mu) * rsig * g0[c] + beta0[c];
            }
        }
    }
    __syncthreads();

    // GEMM2: x1 @ W1 (+b1, relu) -> ybuf
    float acc2[8][4];
    #pragma unroll
    for (int r = 0; r < 8; ++r)
        #pragma unroll
        for (int q = 0; q < 4; ++q) acc2[r][q] = 0.0f;
    for (int e = 0; e < NH; e += 4) {
        float4 x4[8];
        #pragma unroll
        for (int r = 0; r < 8; ++r) x4[r] = *(const float4*)&x1[r][e];
        #pragma unroll
        for (int q = 0; q < 4; ++q) {
            const float* wc = W1 + (size_t)e * NFF + (t + 256 * q);
            const float w0 = wc[0 * NFF], w1 = wc[1 * NFF], w2 = wc[2 * NFF], w3 = wc[3 * NFF];
            #pragma unroll
            for (int r = 0; r < 8; ++r)
                acc2[r][q] = fmaf(x4[r].x, w0, fmaf(x4[r].y, w1, fmaf(x4[r].z, w2, fmaf(x4[r].w, w3, acc2[r][q]))));
        }
    }
    #pragma unroll
    for (int q = 0; q < 4; ++q) {
        const float b1c = b1[t + 256 * q];
        #pragma unroll
        for (int r = 0; r < 8; ++r)
            ybuf[r][t + 256 * q] = fmaxf(acc2[r][q] + b1c, 0.0f);
    }
    __syncthreads();

    // GEMM3: ybuf @ W2 (+b2) + x1 residual
    float acc3[8];
    #pragma unroll
    for (int r = 0; r < 8; ++r) acc3[r] = 0.0f;
    for (int f = 0; f < NFF; f += 4) {
        const float w0 = W2[(size_t)(f + 0) * NH + t];
        const float w1 = W2[(size_t)(f + 1) * NH + t];
        const float w2 = W2[(size_t)(f + 2) * NH + t];
        const float w3 = W2[(size_t)(f + 3) * NH + t];
        #pragma unroll
        for (int r = 0; r < 8; ++r) {
            const float4 y4 = *(const float4*)&ybuf[r][f];
            acc3[r] = fmaf(y4.x, w0, fmaf(y4.y, w1, fmaf(y4.z, w2, fmaf(y4.w, w3, acc3[r]))));
        }
    }
    const float b2c = b2[t];
    #pragma unroll
    for (int r = 0; r < 8; ++r)
        xin[r][t] = x1[r][t] + acc3[r] + b2c;
    __syncthreads();

    // LN1 -> out
    {
        const int wv = t >> 6, ln = t & 63;
        #pragma unroll
        for (int rr = 0; rr < 2; ++rr) {
            const int r = wv * 2 + rr;
            float s1 = 0.0f, s2 = 0.0f;
            #pragma unroll
            for (int k = 0; k < 4; ++k) {
                const float z = xin[r][ln + 64 * k];
                s1 += z; s2 += z * z;
            }
            #pragma unroll
            for (int off = 32; off >= 1; off >>= 1) {
                s1 += __shfl_xor(s1, off);
                s2 += __shfl_xor(s2, off);
            }
            const float mu = s1 * (1.0f / NH);
            const float rsig = rsqrtf(s2 * (1.0f / NH) - mu * mu + LNEPS);
            #pragma unroll
            for (int k = 0; k < 4; ++k) {
                const int c = ln + 64 * k;
                out[(size_t)(row0 + r) * NH + c] = (xin[r][c] - mu) * rsig * g1[c] + beta1[c];
            }
        }
    }
}

// ---------------------------------------------------------------------------
extern "C" void kernel_launch(void* const* d_in, const int* in_sizes, int n_in,
                              void* d_out, int out_size, void* d_ws, size_t ws_size,
                              hipStream_t stream) {
    const float* S     = (const float*)d_in[0];
    const float* T     = (const float*)d_in[1];
    const int*   masks = (const int*)  d_in[2];
    const float* Wqk   = (const float*)d_in[3];
    const float* Wv    = (const float*)d_in[4];
    const float* bv    = (const float*)d_in[5];
    const float* Wo    = (const float*)d_in[6];
    const float* bo    = (const float*)d_in[7];
    const float* g0    = (const float*)d_in[8];
    const float* beta0 = (const float*)d_in[9];
    const float* W1    = (const float*)d_in[10];
    const float* b1    = (const float*)d_in[11];
    const float* W2    = (const float*)d_in[12];
    const float* b2    = (const float*)d_in[13];
    const float* g1    = (const float*)d_in[14];
    const float* beta1 = (const float*)d_in[15];

    float* out      = (float*)d_out;
    float* attn_out = out + (size_t)NB * NN * NH;
    float* v_ws     = (float*)d_ws;
    float* ctx      = out;

    vproj_kernel<<<NB * NN / 8, 256, 0, stream>>>(S, Wv, bv, v_ws);
    attn_kernel<<<NB * NN, 256, 0, stream>>>(T, masks, Wqk, v_ws, attn_out, ctx);
    tail_kernel<<<NB * NN / 8, 256, 0, stream>>>(ctx, S, Wo, bo, g0, beta0,
                                                 W1, b1, W2, b2, g1, beta1, out);
}